// Round 6
// baseline (256.367 us; speedup 1.0000x reference)
//
#include <hip/hip_runtime.h>
#include <hip/hip_bf16.h>
#include <math.h>

typedef __attribute__((ext_vector_type(4))) float f32x4;
typedef __attribute__((ext_vector_type(8))) short s16x8;
typedef __attribute__((ext_vector_type(4))) short s16x4;

#define NB 8
#define NT 2048
#define NC 1024
#define NH 128
// log2(e)/sqrt(C) folded into Q at projection time (exp2-domain softmax)
#define QSCALE 0.04508422002778f
#define PIECES 80   // per batch: sum_j ceil((j+1)/8), j=0..31 (KVCHUNK=512, qtile=64)

__device__ __forceinline__ short f2bf(float f) {
  __hip_bfloat16 h = __float2bfloat16(f);
  union { __hip_bfloat16 h; short s; } u; u.h = h;
  return u.s;
}

__device__ __forceinline__ void glds16(const short* g, short* l) {
  __builtin_amdgcn_global_load_lds(
      (const __attribute__((address_space(1))) unsigned int*)g,
      (__attribute__((address_space(3))) unsigned int*)l, 16, 0, 0);
}

// ---------------- kernel 0: W [C][H] fp32 -> Wt [3][H][C] bf16 --------------
__global__ __launch_bounds__(256)
void wt_kernel(const float* __restrict__ Wq, const float* __restrict__ Wk,
               const float* __restrict__ Wv, short* __restrict__ Wt) {
  __shared__ short T[64 * 72];
  const int tid = threadIdx.x;
  const int k0 = blockIdx.x * 64, n0 = blockIdx.y * 64, proj = blockIdx.z;
  const float* W = (proj == 0) ? Wq : ((proj == 1) ? Wk : Wv);
#pragma unroll
  for (int u = 0; u < 4; u++) {
    int row = u * 16 + (tid >> 4);
    int col4 = (tid & 15) * 4;
    float4 v = *(const float4*)(W + (size_t)(k0 + row) * NH + n0 + col4);
    T[(col4 + 0) * 72 + row] = f2bf(v.x);
    T[(col4 + 1) * 72 + row] = f2bf(v.y);
    T[(col4 + 2) * 72 + row] = f2bf(v.z);
    T[(col4 + 3) * 72 + row] = f2bf(v.w);
  }
  __syncthreads();
#pragma unroll
  for (int u = 0; u < 2; u++) {
    int c = tid + 256 * u;
    int n = c >> 3, c8 = c & 7;
    s16x8 v = *(const s16x8*)(T + n * 72 + c8 * 8);
    *(s16x8*)(Wt + (size_t)proj * (NH * NC) + (size_t)(n0 + n) * NC + k0 + c8 * 8) = v;
  }
}

// ---------------- kernel 1: QKV projection, M-tile 64, 768 blocks ----------
// XCD-trio swizzle: the 3 projections of one m-tile dispatch adjacently on
// the SAME XCD (x-tile read from HBM once, then L2-hit); m-tiles partitioned
// across XCDs. LDS double-buffered A[64][64]+B[128][64] bf16 (48 KiB), B via
// global_load_lds w/ source-XOR-swizzle, A load-early/cvt-write-late (T14).
__global__ __launch_bounds__(256, 3)
void proj_kernel(const float* __restrict__ x, const short* __restrict__ Wt,
                 const float* __restrict__ bq, const float* __restrict__ bk,
                 const float* __restrict__ bv,
                 short* __restrict__ Qb, short* __restrict__ Kb, short* __restrict__ Vtb) {
  __shared__ __align__(16) short smem[2 * 12288];  // per buf: A 4096 + B 8192 shorts

  const int tid = threadIdx.x;
  const int w = tid >> 6, lane = tid & 63;
  const int lr = lane & 15, lg = lane >> 4;

  const int bid = blockIdx.x;          // 768
  const int xcd = bid & 7;
  const int idx = bid >> 3;            // 0..95
  const int proj = idx % 3;
  const int m0 = (xcd * 32 + idx / 3) * 64;

  const int msub = (w & 1) * 32, nsub = (w >> 1) * 64;

  const short* Wtp = Wt + (size_t)proj * (NH * NC);
  // A prefetch: thread t covers row t>>2, float cols (t&3)*16 .. +16
  const int arow = tid >> 2, aq = tid & 3;
  const float* asrc = x + (size_t)(m0 + arow) * NC + aq * 16;

  f32x4 acc[2][4];
#pragma unroll
  for (int i = 0; i < 2; i++)
#pragma unroll
    for (int j = 0; j < 4; j++) acc[i][j] = {0.f, 0.f, 0.f, 0.f};

  float4 pa[2][4];

  auto loadA = [&](int slot, int k0) {
#pragma unroll
    for (int u = 0; u < 4; u++) pa[slot][u] = *(const float4*)(asrc + k0 + u * 4);
  };
  auto writeA = [&](int slot, int buf) {
    short* As = smem + buf * 12288;
#pragma unroll
    for (int h = 0; h < 2; h++) {
      float4 a = pa[slot][2 * h], b2 = pa[slot][2 * h + 1];
      s16x8 v;
      v[0] = f2bf(a.x); v[1] = f2bf(a.y); v[2] = f2bf(a.z); v[3] = f2bf(a.w);
      v[4] = f2bf(b2.x); v[5] = f2bf(b2.y); v[6] = f2bf(b2.z); v[7] = f2bf(b2.w);
      int cc = aq * 2 + h;
      *(s16x8*)(As + arow * 64 + ((cc ^ (arow & 7)) * 8)) = v;
    }
  };
  auto stageB = [&](int buf, int k0) {
    short* Bs = smem + buf * 12288 + 4096;
#pragma unroll
    for (int u = 0; u < 4; u++) {
      int c = u * 256 + w * 64 + lane;       // 0..1023 chunks
      int n = c >> 3, ch = c & 7;
      glds16(Wtp + (size_t)n * NC + k0 + ((ch ^ (n & 7)) * 8),
             Bs + (u * 256 + w * 64) * 8);   // wave-uniform base + lane*16
    }
  };
  auto compute = [&](int buf) {
    const short* As = smem + buf * 12288;
    const short* Bs = smem + buf * 12288 + 4096;
#pragma unroll
    for (int kc = 0; kc < 2; kc++) {
      s16x8 af[2], bf[4];
#pragma unroll
      for (int mi = 0; mi < 2; mi++) {
        int row = msub + mi * 16 + lr;
        af[mi] = *(const s16x8*)(As + row * 64 + (((kc * 4 + lg) ^ (row & 7)) * 8));
      }
#pragma unroll
      for (int ni = 0; ni < 4; ni++) {
        int row = nsub + ni * 16 + lr;
        bf[ni] = *(const s16x8*)(Bs + row * 64 + (((kc * 4 + lg) ^ (row & 7)) * 8));
      }
#pragma unroll
      for (int mi = 0; mi < 2; mi++)
#pragma unroll
        for (int ni = 0; ni < 4; ni++)
          acc[mi][ni] = __builtin_amdgcn_mfma_f32_16x16x32_bf16(af[mi], bf[ni], acc[mi][ni], 0, 0, 0);
    }
  };

  // prologue
  loadA(0, 0);
  stageB(0, 0);
  writeA(0, 0);
  __syncthreads();

  for (int s = 0; s < 16; ++s) {
    int buf = s & 1;
    int slot = (s + 1) & 1;
    if (s < 15) { loadA(slot, (s + 1) * 64); stageB(buf ^ 1, (s + 1) * 64); }
    compute(buf);
    if (s < 15) writeA(slot, buf ^ 1);
    __syncthreads();
  }

  const float* bias = (proj == 0) ? bq : ((proj == 1) ? bk : bv);
  const float scl = (proj == 0) ? QSCALE : 1.0f;
  short* Tr = smem;

  if (proj < 2) {
    // Tr[t][d] t<64 stride 136 -> coalesced row-major write
#pragma unroll
    for (int mi = 0; mi < 2; mi++)
#pragma unroll
      for (int ni = 0; ni < 4; ni++) {
        int d = nsub + ni * 16 + lr;
        float bn = bias[d];
#pragma unroll
        for (int r = 0; r < 4; r++) {
          int t = msub + mi * 16 + lg * 4 + r;
          Tr[t * 136 + d] = f2bf((acc[mi][ni][r] + bn) * scl);
        }
      }
    __syncthreads();
    short* dst = (proj == 0) ? Qb : Kb;
#pragma unroll
    for (int i = 0; i < 4; i++) {
      int c = tid + 256 * i;  // 0..1023
      int t = c >> 4, cc = c & 15;
      s16x8 v = *(const s16x8*)(Tr + t * 136 + cc * 8);
      *(s16x8*)(dst + (size_t)(m0 + t) * NH + cc * 8) = v;
    }
  } else {
    // Tr2[d][t] d<128 stride 72 -> Vt[b][d][t]
#pragma unroll
    for (int mi = 0; mi < 2; mi++)
#pragma unroll
      for (int ni = 0; ni < 4; ni++) {
        int d = nsub + ni * 16 + lr;
        float bn = bias[d];
        int t0 = msub + mi * 16 + lg * 4;
        s16x4 v;
        v[0] = f2bf(acc[mi][ni][0] + bn);
        v[1] = f2bf(acc[mi][ni][1] + bn);
        v[2] = f2bf(acc[mi][ni][2] + bn);
        v[3] = f2bf(acc[mi][ni][3] + bn);
        *(s16x4*)(Tr + d * 72 + t0) = v;
      }
    __syncthreads();
    int b = m0 >> 11, t0g = m0 & 2047;
#pragma unroll
    for (int i = 0; i < 4; i++) {
      int c = tid + 256 * i;  // 0..1023
      int d = c >> 3, cc = c & 7;
      s16x8 v = *(const s16x8*)(Tr + d * 72 + cc * 8);
      *(s16x8*)(Vtb + (size_t)b * (NH * NT) + (size_t)d * NT + t0g + cc * 8) = v;
    }
  }
}

// ---------------- kernel 2: split-KV flash attention + fan-in combine ------
// grid (8 batches, 80 pieces). KVSTEP=64 double-buffered (64 KiB LDS).
// P==1 pieces write out directly. P>1 pieces write fp32 partials + (m,l),
// then release-fence + atomicAdd a group counter; the LAST block of each
// (batch, q-tile) group acquire-fences and combines in-place (no 4th kernel).
__global__ __launch_bounds__(256, 2)
void attn_partial(const short* __restrict__ Qb, const short* __restrict__ Kb,
                  const short* __restrict__ Vtb, float* __restrict__ out,
                  float* __restrict__ part, float* __restrict__ partml,
                  int* __restrict__ cnt) {
  __shared__ __align__(16) short smem[32768];  // K[2][64][128] @0, V[2][128][64] @16384
  __shared__ int s_flag;

  const int tid = threadIdx.x;
  const int w = tid >> 6, lane = tid & 63;
  const int lr = lane & 15, lg = lane >> 4;

  const int batch = blockIdx.x;
  const int r = (PIECES - 1) - blockIdx.y;  // heavy pieces first
  int j = 0, pfx0 = 0;
  while (pfx0 + (j >> 3) + 1 <= r) { pfx0 += (j >> 3) + 1; j++; }
  const int c = r - pfx0;
  const int P = (j >> 3) + 1;
  const int q0 = j * 64;
  const int kv_begin = c * 512;
  const int kv_end = min(kv_begin + 512, (j + 1) * 64);
  const int nsteps = (kv_end - kv_begin) >> 6;

  const short* Kp = Kb + (size_t)batch * NT * NH;
  const short* Vp = Vtb + (size_t)batch * NH * NT;
  const int q = q0 + w * 16 + lr;

  const short* Qrow = Qb + (size_t)(batch * NT + q) * NH;
  s16x8 qf[4];
#pragma unroll
  for (int dc = 0; dc < 4; dc++) qf[dc] = *(const s16x8*)(Qrow + dc * 32 + lg * 8);

  f32x4 acc[8];
#pragma unroll
  for (int i = 0; i < 8; i++) acc[i] = {0.f, 0.f, 0.f, 0.f};
  float m_run = -3.0e38f, l_run = 0.f;

  auto stage = [&](int buf, int kv0) {
#pragma unroll
    for (int u = 0; u < 4; u++) {  // K tile [64][128]: 1024 chunks
      int c2 = u * 256 + w * 64 + lane;
      int row = c2 >> 4, ch = c2 & 15;
      int sch = (ch & 8) | ((ch & 7) ^ (row & 7));
      glds16(Kp + (size_t)(kv0 + row) * NH + sch * 8,
             smem + buf * 8192 + (u * 256 + w * 64) * 8);
    }
#pragma unroll
    for (int u = 0; u < 4; u++) {  // V tile [128][64]: 1024 chunks
      int c2 = u * 256 + w * 64 + lane;
      int d = c2 >> 3, ch = c2 & 7;
      int sch = ch ^ (d & 7);
      glds16(Vp + (size_t)d * NT + kv0 + sch * 8,
             smem + 16384 + buf * 8192 + (u * 256 + w * 64) * 8);
    }
  };

  stage(0, kv_begin);
  __syncthreads();

  for (int s = 0; s < nsteps; s++) {
    const int buf = s & 1;
    const int kv0 = kv_begin + s * 64;
    if (s + 1 < nsteps) stage(buf ^ 1, kv0 + 64);

    const short* Kl = smem + buf * 8192;
    const short* Vl = smem + 16384 + buf * 8192;

    f32x4 st[4];
#pragma unroll
    for (int sub = 0; sub < 4; sub++) st[sub] = {0.f, 0.f, 0.f, 0.f};
#pragma unroll
    for (int dc = 0; dc < 4; dc++) {
      int ch = dc * 4 + lg;
      int sch = (ch & 8) | ((ch & 7) ^ (lr & 7));
#pragma unroll
      for (int sub = 0; sub < 4; sub++) {
        s16x8 kf = *(const s16x8*)(Kl + (sub * 16 + lr) * 128 + sch * 8);
        st[sub] = __builtin_amdgcn_mfma_f32_16x16x32_bf16(kf, qf[dc], st[sub], 0, 0, 0);
      }
    }
    if (kv0 + 63 > q0) {  // diagonal: causal mask
#pragma unroll
      for (int sub = 0; sub < 4; sub++)
#pragma unroll
        for (int rr = 0; rr < 4; rr++)
          if (kv0 + sub * 16 + lg * 4 + rr > q) st[sub][rr] = -3.0e38f;
    }
    float tm = -3.0e38f;
#pragma unroll
    for (int sub = 0; sub < 4; sub++)
#pragma unroll
      for (int rr = 0; rr < 4; rr++) tm = fmaxf(tm, st[sub][rr]);
    tm = fmaxf(tm, __shfl_xor(tm, 16, 64));
    tm = fmaxf(tm, __shfl_xor(tm, 32, 64));
    float m_new = fmaxf(m_run, tm);
    float corr = exp2f(m_run - m_new);
    float psum = 0.f;
    s16x8 pf[2];
#pragma unroll
    for (int sub = 0; sub < 4; sub++)
#pragma unroll
      for (int rr = 0; rr < 4; rr++) {
        float p = exp2f(st[sub][rr] - m_new);
        psum += p;
        pf[sub >> 1][(sub & 1) * 4 + rr] = f2bf(p);
      }
    psum += __shfl_xor(psum, 16, 64);
    psum += __shfl_xor(psum, 32, 64);
    l_run = l_run * corr + psum;
    m_run = m_new;
#pragma unroll
    for (int i = 0; i < 8; i++) acc[i] *= corr;
    // PV: k-slot layout matches st/pf ownership (permuted slots, no shuffle)
#pragma unroll
    for (int ks = 0; ks < 2; ks++)
#pragma unroll
      for (int dm = 0; dm < 8; dm++) {
        int d = dm * 16 + lr;
        const short* vb = Vl + d * 64;
        int ch0 = (ks * 4 + (lg >> 1)) ^ (d & 7);
        int ch1 = ch0 ^ 2;
        s16x4 v0 = *(const s16x4*)(vb + ch0 * 8 + (lg & 1) * 4);
        s16x4 v1 = *(const s16x4*)(vb + ch1 * 8 + (lg & 1) * 4);
        s16x8 vf = __builtin_shufflevector(v0, v1, 0, 1, 2, 3, 4, 5, 6, 7);
        acc[dm] = __builtin_amdgcn_mfma_f32_16x16x32_bf16(vf, pf[ks], acc[dm], 0, 0, 0);
      }
    __syncthreads();
  }

  if (P == 1) {
    const float inv = 1.f / l_run;
    float* orow = out + (size_t)(batch * NT + q) * NH;
#pragma unroll
    for (int dm = 0; dm < 8; dm++) {
      f32x4 v = acc[dm] * inv;
      *(f32x4*)(orow + dm * 16 + lg * 4) = v;
    }
    return;
  }

  // ---- write partials ----
  {
    float* pb = part + ((size_t)batch * PIECES + r) * 8192;
    int ql0 = w * 16 + lr;
#pragma unroll
    for (int dm = 0; dm < 8; dm++)
      *(f32x4*)(pb + ql0 * 128 + dm * 16 + lg * 4) = acc[dm];
    if (lg == 0) {
      float2* ml = (float2*)partml + ((size_t)batch * PIECES + r) * 64;
      ml[ql0] = make_float2(m_run, l_run);
    }
  }
  // ---- release + fan-in: last block of the group combines ----
  __threadfence();
  __syncthreads();
  if (tid == 0) {
    int gid = batch * 24 + (j - 8);   // P>1 <=> j>=8; 24 groups/batch
    s_flag = (atomicAdd(&cnt[gid], 1) == P - 1) ? 1 : 0;
  }
  __syncthreads();
  if (!s_flag) return;
  __threadfence();  // acquire

  {
    const int pfx = r - c;
    const int ql = tid >> 2, d0 = (tid & 3) * 32;
    const float2* mlb = (const float2*)partml + ((size_t)batch * PIECES + pfx) * 64 + ql;
    float M = -3.0e38f;
    for (int p = 0; p < P; p++) M = fmaxf(M, mlb[p * 64].x);
    float L = 0.f;
    f32x4 o[8];
#pragma unroll
    for (int u = 0; u < 8; u++) o[u] = {0.f, 0.f, 0.f, 0.f};
    for (int p = 0; p < P; p++) {
      float2 ml2 = mlb[p * 64];
      float wgt = exp2f(ml2.x - M);
      L += wgt * ml2.y;
      const float* pb2 = part + ((size_t)batch * PIECES + pfx + p) * 8192 + ql * 128 + d0;
#pragma unroll
      for (int u = 0; u < 8; u++) o[u] += wgt * *(const f32x4*)(pb2 + u * 4);
    }
    const float inv = 1.f / L;
    float* orow = out + ((size_t)batch * NT + q0 + ql) * NH + d0;
#pragma unroll
    for (int u = 0; u < 8; u++) *(f32x4*)(orow + u * 4) = o[u] * inv;
  }
}

// ---------------- launch ----------------------------------------------------
extern "C" void kernel_launch(void* const* d_in, const int* in_sizes, int n_in,
                              void* d_out, int out_size, void* d_ws, size_t ws_size,
                              hipStream_t stream) {
  const float* x = (const float*)d_in[0];
  const float* Wq = (const float*)d_in[1];
  const float* bq = (const float*)d_in[2];
  const float* Wk = (const float*)d_in[3];
  const float* bk = (const float*)d_in[4];
  const float* Wv = (const float*)d_in[5];
  const float* bv = (const float*)d_in[6];
  float* out = (float*)d_out;

  char* ws = (char*)d_ws;
  short* Wt = (short*)ws;                                  // 786,432 B
  short* Qb = (short*)(ws + 786432);                       // 4 MiB
  short* Kb = (short*)(ws + 786432 + 4194304);             // 4 MiB
  short* Vtb = (short*)(ws + 786432 + 2 * 4194304);        // 4 MiB
  float* part = (float*)(ws + 13369344);                   // 20,971,520 B
  float* partml = (float*)(ws + 13369344 + 20971520);      // 327,680 B
  int* cnt = (int*)(ws + 13369344 + 20971520 + 327680);    // 768 B (8*24 counters)

  hipMemsetAsync(cnt, 0, 8 * 24 * sizeof(int), stream);
  wt_kernel<<<dim3(16, 2, 3), dim3(256), 0, stream>>>(Wq, Wk, Wv, Wt);
  proj_kernel<<<dim3(768), dim3(256), 0, stream>>>(x, Wt, bq, bk, bv, Qb, Kb, Vtb);
  attn_partial<<<dim3(8, PIECES), dim3(256), 0, stream>>>(Qb, Kb, Vtb, out, part, partml, cnt);
}

// Round 7
// 205.580 us; speedup vs baseline: 1.2470x; 1.2470x over previous
//
#include <hip/hip_runtime.h>
#include <hip/hip_bf16.h>
#include <math.h>

typedef __attribute__((ext_vector_type(4))) float f32x4;
typedef __attribute__((ext_vector_type(8))) short s16x8;
typedef __attribute__((ext_vector_type(4))) short s16x4;

#define NB 8
#define NT 2048
#define NC 1024
#define NH 128
// log2(e)/sqrt(C) folded into Q at projection time (exp2-domain softmax)
#define QSCALE 0.04508422002778f
#define PIECES 80   // per batch: sum_j ceil((j+1)/8), j=0..31 (KVCHUNK=512, qtile=64)

__device__ __forceinline__ short f2bf(float f) {
  __hip_bfloat16 h = __float2bfloat16(f);
  union { __hip_bfloat16 h; short s; } u; u.h = h;
  return u.s;
}

__device__ __forceinline__ void glds16(const short* g, short* l) {
  __builtin_amdgcn_global_load_lds(
      (const __attribute__((address_space(1))) unsigned int*)g,
      (__attribute__((address_space(3))) unsigned int*)l, 16, 0, 0);
}

// ---------------- kernel 0: W [C][H] fp32 -> Wt [3][H][C] bf16 --------------
__global__ __launch_bounds__(256)
void wt_kernel(const float* __restrict__ Wq, const float* __restrict__ Wk,
               const float* __restrict__ Wv, short* __restrict__ Wt) {
  __shared__ short T[64 * 72];
  const int tid = threadIdx.x;
  const int k0 = blockIdx.x * 64, n0 = blockIdx.y * 64, proj = blockIdx.z;
  const float* W = (proj == 0) ? Wq : ((proj == 1) ? Wk : Wv);
#pragma unroll
  for (int u = 0; u < 4; u++) {
    int row = u * 16 + (tid >> 4);
    int col4 = (tid & 15) * 4;
    float4 v = *(const float4*)(W + (size_t)(k0 + row) * NH + n0 + col4);
    T[(col4 + 0) * 72 + row] = f2bf(v.x);
    T[(col4 + 1) * 72 + row] = f2bf(v.y);
    T[(col4 + 2) * 72 + row] = f2bf(v.z);
    T[(col4 + 3) * 72 + row] = f2bf(v.w);
  }
  __syncthreads();
#pragma unroll
  for (int u = 0; u < 2; u++) {
    int c = tid + 256 * u;
    int n = c >> 3, c8 = c & 7;
    s16x8 v = *(const s16x8*)(T + n * 72 + c8 * 8);
    *(s16x8*)(Wt + (size_t)proj * (NH * NC) + (size_t)(n0 + n) * NC + k0 + c8 * 8) = v;
  }
}

// ---------------- kernel 1: QKV projection, M-tile 32, A-in-registers ------
// 1536 blocks (6/CU), XCD-trio swizzle: xcd = bid&7, idx = bid>>3,
// proj = idx%3, m0 = (xcd*64 + idx/3)*32. 4 waves in 2Mx2N grid
// (msub = (w&1)*16, nsub = (w>>1)*64). A never touches LDS: each lane loads
// its own fp32 rows (32B contiguous), cvt to bf16 in-reg, one step ahead.
// B: LDS double-buffer [2][128][64] bf16 (32 KiB) via global_load_lds with
// source-XOR swizzle. One barrier per k-step; only B loads gate the barrier.
__global__ __launch_bounds__(256, 4)
void proj_kernel(const float* __restrict__ x, const short* __restrict__ Wt,
                 const float* __restrict__ bq, const float* __restrict__ bk,
                 const float* __restrict__ bv,
                 short* __restrict__ Qb, short* __restrict__ Kb, short* __restrict__ Vtb) {
  __shared__ __align__(16) short Bs[2][8192];  // [128][64] per buf; epilogue reuses Bs[0]

  const int tid = threadIdx.x;
  const int w = tid >> 6, lane = tid & 63;
  const int lr = lane & 15, lg = lane >> 4;

  const int bid = blockIdx.x;          // 1536
  const int xcd = bid & 7;
  const int idx = bid >> 3;            // 0..191
  const int proj = idx % 3;
  const int m0 = (xcd * 64 + idx / 3) * 32;

  const int msub = (w & 1) * 16, nsub = (w >> 1) * 64;

  const short* Wtp = Wt + (size_t)proj * (NH * NC);
  const float* arow = x + (size_t)(m0 + msub + lr) * NC;  // this lane's A row

  f32x4 acc[4];
#pragma unroll
  for (int i = 0; i < 4; i++) acc[i] = {0.f, 0.f, 0.f, 0.f};

  float4 pa[2][2], pn[2][2];  // [kc][half-of-8-floats]

  auto loadA = [&](float4 (&dst)[2][2], int k0) {
#pragma unroll
    for (int kc = 0; kc < 2; kc++)
#pragma unroll
      for (int h = 0; h < 2; h++)
        dst[kc][h] = *(const float4*)(arow + k0 + kc * 32 + lg * 8 + h * 4);
  };
  auto stageB = [&](int buf, int k0) {
#pragma unroll
    for (int u = 0; u < 4; u++) {
      int c = u * 256 + w * 64 + lane;       // 0..1023 16B-chunks
      int n = c >> 3, ch = c & 7;
      glds16(Wtp + (size_t)n * NC + k0 + ((ch ^ (n & 7)) * 8),
             &Bs[buf][(u * 256 + w * 64) * 8]);   // wave-uniform base
    }
  };
  auto compute = [&](int buf, float4 (&cur)[2][2]) {
#pragma unroll
    for (int kc = 0; kc < 2; kc++) {
      float4 a = cur[kc][0], b2 = cur[kc][1];
      s16x8 af;
      af[0] = f2bf(a.x); af[1] = f2bf(a.y); af[2] = f2bf(a.z); af[3] = f2bf(a.w);
      af[4] = f2bf(b2.x); af[5] = f2bf(b2.y); af[6] = f2bf(b2.z); af[7] = f2bf(b2.w);
#pragma unroll
      for (int ni = 0; ni < 4; ni++) {
        int row = nsub + ni * 16 + lr;
        s16x8 bf = *(const s16x8*)(&Bs[buf][row * 64 + (((kc * 4 + lg) ^ (row & 7)) * 8)]);
        acc[ni] = __builtin_amdgcn_mfma_f32_16x16x32_bf16(af, bf, acc[ni], 0, 0, 0);
      }
    }
  };
  auto step = [&](int s, float4 (&cur)[2][2], float4 (&nxt)[2][2]) {
    if (s < 15) { loadA(nxt, (s + 1) * 64); stageB((s & 1) ^ 1, (s + 1) * 64); }
    compute(s & 1, cur);
    __syncthreads();
  };

  // prologue
  loadA(pa, 0);
  stageB(0, 0);
  __syncthreads();

  for (int ss = 0; ss < 8; ss++) { step(2 * ss, pa, pn); step(2 * ss + 1, pn, pa); }

  const float* bias = (proj == 0) ? bq : ((proj == 1) ? bk : bv);
  const float scl = (proj == 0) ? QSCALE : 1.0f;
  short* Tr = &Bs[0][0];

  if (proj < 2) {
    // Tr[t][d] t<32 stride 136 -> coalesced row-major out
#pragma unroll
    for (int ni = 0; ni < 4; ni++) {
      int d = nsub + ni * 16 + lr;
      float bn = bias[d];
#pragma unroll
      for (int r = 0; r < 4; r++) {
        int t = msub + lg * 4 + r;
        Tr[t * 136 + d] = f2bf((acc[ni][r] + bn) * scl);
      }
    }
    __syncthreads();
    short* dst = (proj == 0) ? Qb : Kb;
#pragma unroll
    for (int i = 0; i < 2; i++) {
      int c = tid + 256 * i;  // 0..511
      int t = c >> 4, cc = c & 15;
      s16x8 v = *(const s16x8*)(Tr + t * 136 + cc * 8);
      *(s16x8*)(dst + (size_t)(m0 + t) * NH + cc * 8) = v;
    }
  } else {
    // Tr2[d][t] d<128 stride 40 -> Vt[b][d][t]
#pragma unroll
    for (int ni = 0; ni < 4; ni++) {
      int d = nsub + ni * 16 + lr;
      float bn = bias[d];
      int t0 = msub + lg * 4;
      s16x4 v;
      v[0] = f2bf(acc[ni][0] + bn);
      v[1] = f2bf(acc[ni][1] + bn);
      v[2] = f2bf(acc[ni][2] + bn);
      v[3] = f2bf(acc[ni][3] + bn);
      *(s16x4*)(Tr + d * 40 + t0) = v;
    }
    __syncthreads();
    int b = m0 >> 11, t0g = m0 & 2047;
#pragma unroll
    for (int i = 0; i < 2; i++) {
      int c = tid + 256 * i;  // 0..511
      int d = c >> 2, cc = c & 3;
      s16x8 v = *(const s16x8*)(Tr + d * 40 + cc * 8);
      *(s16x8*)(Vtb + (size_t)b * (NH * NT) + (size_t)d * NT + t0g + cc * 8) = v;
    }
  }
}

// ---------------- kernel 2: split-KV flash attention partials --------------
// grid (8 batches, 80 pieces). KVSTEP=64 double-buffered (64 KiB LDS).
// (R5-proven version: no fences, no atomics.)
__global__ __launch_bounds__(256, 2)
void attn_partial(const short* __restrict__ Qb, const short* __restrict__ Kb,
                  const short* __restrict__ Vtb, float* __restrict__ out,
                  float* __restrict__ part, float* __restrict__ partml) {
  __shared__ __align__(16) short smem[32768];  // K[2][64][128] @0, V[2][128][64] @16384

  const int tid = threadIdx.x;
  const int w = tid >> 6, lane = tid & 63;
  const int lr = lane & 15, lg = lane >> 4;

  const int batch = blockIdx.x;
  const int r = (PIECES - 1) - blockIdx.y;  // heavy pieces first
  int j = 0, pfx0 = 0;
  while (pfx0 + (j >> 3) + 1 <= r) { pfx0 += (j >> 3) + 1; j++; }
  const int c = r - pfx0;
  const int P = (j >> 3) + 1;
  const int q0 = j * 64;
  const int kv_begin = c * 512;
  const int kv_end = min(kv_begin + 512, (j + 1) * 64);
  const int nsteps = (kv_end - kv_begin) >> 6;

  const short* Kp = Kb + (size_t)batch * NT * NH;
  const short* Vp = Vtb + (size_t)batch * NH * NT;
  const int q = q0 + w * 16 + lr;

  const short* Qrow = Qb + (size_t)(batch * NT + q) * NH;
  s16x8 qf[4];
#pragma unroll
  for (int dc = 0; dc < 4; dc++) qf[dc] = *(const s16x8*)(Qrow + dc * 32 + lg * 8);

  f32x4 acc[8];
#pragma unroll
  for (int i = 0; i < 8; i++) acc[i] = {0.f, 0.f, 0.f, 0.f};
  float m_run = -3.0e38f, l_run = 0.f;

  auto stage = [&](int buf, int kv0) {
#pragma unroll
    for (int u = 0; u < 4; u++) {  // K tile [64][128]: 1024 chunks
      int c2 = u * 256 + w * 64 + lane;
      int row = c2 >> 4, ch = c2 & 15;
      int sch = (ch & 8) | ((ch & 7) ^ (row & 7));
      glds16(Kp + (size_t)(kv0 + row) * NH + sch * 8,
             smem + buf * 8192 + (u * 256 + w * 64) * 8);
    }
#pragma unroll
    for (int u = 0; u < 4; u++) {  // V tile [128][64]: 1024 chunks
      int c2 = u * 256 + w * 64 + lane;
      int d = c2 >> 3, ch = c2 & 7;
      int sch = ch ^ (d & 7);
      glds16(Vp + (size_t)d * NT + kv0 + sch * 8,
             smem + 16384 + buf * 8192 + (u * 256 + w * 64) * 8);
    }
  };

  stage(0, kv_begin);
  __syncthreads();

  for (int s = 0; s < nsteps; s++) {
    const int buf = s & 1;
    const int kv0 = kv_begin + s * 64;
    if (s + 1 < nsteps) stage(buf ^ 1, kv0 + 64);

    const short* Kl = smem + buf * 8192;
    const short* Vl = smem + 16384 + buf * 8192;

    f32x4 st[4];
#pragma unroll
    for (int sub = 0; sub < 4; sub++) st[sub] = {0.f, 0.f, 0.f, 0.f};
#pragma unroll
    for (int dc = 0; dc < 4; dc++) {
      int ch = dc * 4 + lg;
      int sch = (ch & 8) | ((ch & 7) ^ (lr & 7));
#pragma unroll
      for (int sub = 0; sub < 4; sub++) {
        s16x8 kf = *(const s16x8*)(Kl + (sub * 16 + lr) * 128 + sch * 8);
        st[sub] = __builtin_amdgcn_mfma_f32_16x16x32_bf16(kf, qf[dc], st[sub], 0, 0, 0);
      }
    }
    if (kv0 + 63 > q0) {  // diagonal: causal mask
#pragma unroll
      for (int sub = 0; sub < 4; sub++)
#pragma unroll
        for (int rr = 0; rr < 4; rr++)
          if (kv0 + sub * 16 + lg * 4 + rr > q) st[sub][rr] = -3.0e38f;
    }
    float tm = -3.0e38f;
#pragma unroll
    for (int sub = 0; sub < 4; sub++)
#pragma unroll
      for (int rr = 0; rr < 4; rr++) tm = fmaxf(tm, st[sub][rr]);
    tm = fmaxf(tm, __shfl_xor(tm, 16, 64));
    tm = fmaxf(tm, __shfl_xor(tm, 32, 64));
    float m_new = fmaxf(m_run, tm);
    float corr = exp2f(m_run - m_new);
    float psum = 0.f;
    s16x8 pf[2];
#pragma unroll
    for (int sub = 0; sub < 4; sub++)
#pragma unroll
      for (int rr = 0; rr < 4; rr++) {
        float p = exp2f(st[sub][rr] - m_new);
        psum += p;
        pf[sub >> 1][(sub & 1) * 4 + rr] = f2bf(p);
      }
    psum += __shfl_xor(psum, 16, 64);
    psum += __shfl_xor(psum, 32, 64);
    l_run = l_run * corr + psum;
    m_run = m_new;
#pragma unroll
    for (int i = 0; i < 8; i++) acc[i] *= corr;
    // PV: k-slot layout matches st/pf ownership (permuted slots, no shuffle)
#pragma unroll
    for (int ks = 0; ks < 2; ks++)
#pragma unroll
      for (int dm = 0; dm < 8; dm++) {
        int d = dm * 16 + lr;
        const short* vb = Vl + d * 64;
        int ch0 = (ks * 4 + (lg >> 1)) ^ (d & 7);
        int ch1 = ch0 ^ 2;
        s16x4 v0 = *(const s16x4*)(vb + ch0 * 8 + (lg & 1) * 4);
        s16x4 v1 = *(const s16x4*)(vb + ch1 * 8 + (lg & 1) * 4);
        s16x8 vf = __builtin_shufflevector(v0, v1, 0, 1, 2, 3, 4, 5, 6, 7);
        acc[dm] = __builtin_amdgcn_mfma_f32_16x16x32_bf16(vf, pf[ks], acc[dm], 0, 0, 0);
      }
    __syncthreads();
  }

  if (P == 1) {
    const float inv = 1.f / l_run;
    float* orow = out + (size_t)(batch * NT + q) * NH;
#pragma unroll
    for (int dm = 0; dm < 8; dm++) {
      f32x4 v = acc[dm] * inv;
      *(f32x4*)(orow + dm * 16 + lg * 4) = v;
    }
  } else {
    float* pb = part + ((size_t)batch * PIECES + r) * 8192;
    int ql = w * 16 + lr;
#pragma unroll
    for (int dm = 0; dm < 8; dm++)
      *(f32x4*)(pb + ql * 128 + dm * 16 + lg * 4) = acc[dm];
    if (lg == 0) {
      float2* ml = (float2*)partml + ((size_t)batch * PIECES + r) * 64;
      ml[ql] = make_float2(m_run, l_run);
    }
  }
}

// ---------------- kernel 3: combine partials for j>=8 ----------------------
__global__ __launch_bounds__(256)
void attn_combine(const float* __restrict__ part, const float* __restrict__ partml,
                  float* __restrict__ out) {
  const int batch = blockIdx.x;
  const int j = 8 + blockIdx.y;
  int pfx = 0;
  for (int jj = 0; jj < j; jj++) pfx += (jj >> 3) + 1;
  const int P = (j >> 3) + 1;
  const int tid = threadIdx.x;
  const int ql = tid >> 2, d0 = (tid & 3) * 32;

  const float2* mlb = (const float2*)partml + ((size_t)batch * PIECES + pfx) * 64 + ql;
  float M = -3.0e38f;
  for (int p = 0; p < P; p++) M = fmaxf(M, mlb[p * 64].x);
  float L = 0.f;
  f32x4 o[8];
#pragma unroll
  for (int u = 0; u < 8; u++) o[u] = {0.f, 0.f, 0.f, 0.f};
  for (int p = 0; p < P; p++) {
    float2 ml = mlb[p * 64];
    float wgt = exp2f(ml.x - M);
    L += wgt * ml.y;
    const float* pb = part + ((size_t)batch * PIECES + pfx + p) * 8192 + ql * 128 + d0;
#pragma unroll
    for (int u = 0; u < 8; u++) o[u] += wgt * *(const f32x4*)(pb + u * 4);
  }
  const float inv = 1.f / L;
  float* orow = out + ((size_t)batch * NT + j * 64 + ql) * NH + d0;
#pragma unroll
  for (int u = 0; u < 8; u++) *(f32x4*)(orow + u * 4) = o[u] * inv;
}

// ---------------- launch ----------------------------------------------------
extern "C" void kernel_launch(void* const* d_in, const int* in_sizes, int n_in,
                              void* d_out, int out_size, void* d_ws, size_t ws_size,
                              hipStream_t stream) {
  const float* x = (const float*)d_in[0];
  const float* Wq = (const float*)d_in[1];
  const float* bq = (const float*)d_in[2];
  const float* Wk = (const float*)d_in[3];
  const float* bk = (const float*)d_in[4];
  const float* Wv = (const float*)d_in[5];
  const float* bv = (const float*)d_in[6];
  float* out = (float*)d_out;

  char* ws = (char*)d_ws;
  short* Wt = (short*)ws;                                  // 786,432 B
  short* Qb = (short*)(ws + 786432);                       // 4 MiB
  short* Kb = (short*)(ws + 786432 + 4194304);             // 4 MiB
  short* Vtb = (short*)(ws + 786432 + 2 * 4194304);        // 4 MiB
  float* part = (float*)(ws + 13369344);                   // 20,971,520 B
  float* partml = (float*)(ws + 13369344 + 20971520);      // 327,680 B (total ~33 MiB)

  wt_kernel<<<dim3(16, 2, 3), dim3(256), 0, stream>>>(Wq, Wk, Wv, Wt);
  proj_kernel<<<dim3(1536), dim3(256), 0, stream>>>(x, Wt, bq, bk, bv, Qb, Kb, Vtb);
  attn_partial<<<dim3(8, PIECES), dim3(256), 0, stream>>>(Qb, Kb, Vtb, out, part, partml);
  attn_combine<<<dim3(8, 24), dim3(256), 0, stream>>>(part, partml, out);
}